// Round 4
// baseline (279.977 us; speedup 1.0000x reference)
//
#include <hip/hip_runtime.h>

#define NPTS 2048
#define NPATCH 32
#define FLOATS_PER_BATCH (NPTS*3)   // 6144 floats = 1536 float4
#define N_PAIRS 528.0f              // 32*33/2

// Stage 1: one WAVE per batch element. Block = 256 (4 waves), grid = B/4.
// Zero LDS, zero __syncthreads -> no vmcnt(0) barrier drains; waves
// self-stagger so loads stay in flight during pair-phase tails.
//
// Lane l: patch p = l>>1, half h = l&1. Reads float4 idx 48p + 2j + h
// (j=0..23): lane pairs read adjacent float4s, patch region fully consumed.
// Component c of v[j] is true coordinate (2j + h + c) % 3. Accumulate into
// local frame m = (2j + c) % 3 (compile-time), un-rotate once on h.
__global__ __launch_bounds__(256) void patch_stage1(
    const float* __restrict__ pcs, float* __restrict__ ws) {
  const int tid  = threadIdx.x;
  const int lane = tid & 63;
  const int h    = lane & 1;
  const int b    = blockIdx.x * 4 + (tid >> 6);

  const float4* p4 = (const float4*)(pcs + (size_t)b * FLOATS_PER_BATCH)
                     + 48 * (lane >> 1) + h;

  float4 v[24];
#pragma unroll
  for (int j = 0; j < 24; ++j) v[j] = p4[2 * j];

  float L0 = 0.f, L1 = 0.f, L2 = 0.f;
  float Q0 = 0.f, Q1 = 0.f, Q2 = 0.f;

#define ACC(j, a, bb, c)                                         \
  { float x = v[j].x, y = v[j].y, z = v[j].z, w = v[j].w;        \
    L##a += x + w; Q##a += x * x + w * w;                        \
    L##bb += y;    Q##bb += y * y;                               \
    L##c += z;     Q##c += z * z; }
  // j%3==0 -> (0,1,2); j%3==1 -> (2,0,1); j%3==2 -> (1,2,0)
  ACC(0,0,1,2)  ACC(1,2,0,1)  ACC(2,1,2,0)
  ACC(3,0,1,2)  ACC(4,2,0,1)  ACC(5,1,2,0)
  ACC(6,0,1,2)  ACC(7,2,0,1)  ACC(8,1,2,0)
  ACC(9,0,1,2)  ACC(10,2,0,1) ACC(11,1,2,0)
  ACC(12,0,1,2) ACC(13,2,0,1) ACC(14,1,2,0)
  ACC(15,0,1,2) ACC(16,2,0,1) ACC(17,1,2,0)
  ACC(18,0,1,2) ACC(19,2,0,1) ACC(20,1,2,0)
  ACC(21,0,1,2) ACC(22,2,0,1) ACC(23,1,2,0)
#undef ACC

  // Un-rotate: L[m] holds true coordinate (m + h) % 3.
  float sx, sy, sz, sxx, syy, szz;
  if (h == 0) { sx = L0; sy = L1; sz = L2; sxx = Q0; syy = Q1; szz = Q2; }
  else        { sx = L2; sy = L0; sz = L1; sxx = Q2; syy = Q0; szz = Q1; }

  // reduce across the lane pair; both lanes end with full patch sums
  sx  += __shfl_xor(sx,  1);
  sy  += __shfl_xor(sy,  1);
  sz  += __shfl_xor(sz,  1);
  sxx += __shfl_xor(sxx, 1);
  syy += __shfl_xor(syy, 1);
  szz += __shfl_xor(szz, 1);

  const float inv_n = 1.0f / 64.0f, inv_nm1 = 1.0f / 63.0f;
  const float mx = sx * inv_n, my = sy * inv_n, mz = sz * inv_n;
  const float tx = sqrtf(fmaxf((sxx - sx * sx * inv_n) * inv_nm1, 0.f));
  const float ty = sqrtf(fmaxf((syy - sy * sy * inv_n) * inv_nm1, 0.f));
  const float tz = sqrtf(fmaxf((szz - sz * sz * inv_n) * inv_nm1, 0.f));

  // Pair phase, LDS-free: lane (p,h) does ordered pairs (p, (p+16h+rr)%32),
  // rr=0..15. src lane (l + 32h + 2rr) & 63 holds that patch's stats (same
  // h slot). All 1024 ordered pairs covered exactly once across the wave.
  // sum_{i<=j} = (sum_ordered + diag)/2; diag (h==0, rr==0) counted twice,
  // then everything halved.
  float acc = 0.f;
  const int sbase = lane + 32 * h;
#pragma unroll
  for (int rr = 0; rr < 16; ++rr) {
    const int src = (sbase + 2 * rr) & 63;
    const float qmx = __shfl(mx, src), qmy = __shfl(my, src), qmz = __shfl(mz, src);
    const float qtx = __shfl(tx, src), qty = __shfl(ty, src), qtz = __shfl(tz, src);
    const float rx = fmaxf((tx + qtx) - fabsf(mx - qmx), 0.f);
    const float ry = fmaxf((ty + qty) - fabsf(my - qmy), 0.f);
    const float rz = fmaxf((tz + qtz) - fabsf(mz - qmz), 0.f);
    const float nrm = sqrtf(rx * rx + ry * ry + rz * rz);
    acc += ((rr == 0) & (h == 0)) ? 2.0f * nrm : nrm;
  }
  acc *= 0.5f;

  // wave reduce, lane 0 writes the batch partial
#pragma unroll
  for (int off = 32; off >= 1; off >>= 1) acc += __shfl_down(acc, off);
  if (lane == 0) ws[b] = acc;
}

// Stage 2: single block reduces the B per-batch partials, scales, writes out.
__global__ __launch_bounds__(256) void patch_stage2(
    const float* __restrict__ ws, float* __restrict__ out, int n, float scale) {
  float acc = 0.f;
  for (int i = threadIdx.x; i < n; i += 256) acc += ws[i];
#pragma unroll
  for (int off = 32; off >= 1; off >>= 1) acc += __shfl_down(acc, off);
  __shared__ float wpart[4];
  if ((threadIdx.x & 63) == 0) wpart[threadIdx.x >> 6] = acc;
  __syncthreads();
  if (threadIdx.x == 0) out[0] = (wpart[0] + wpart[1] + wpart[2] + wpart[3]) * scale;
}

extern "C" void kernel_launch(void* const* d_in, const int* in_sizes, int n_in,
                              void* d_out, int out_size, void* d_ws, size_t ws_size,
                              hipStream_t stream) {
  const float* pcs = (const float*)d_in[0];
  float* out = (float*)d_out;
  float* ws  = (float*)d_ws;

  const int B = in_sizes[0] / FLOATS_PER_BATCH;   // 8192
  const float scale = 1.0f / (N_PAIRS * (float)B);

  patch_stage1<<<B / 4, 256, 0, stream>>>(pcs, ws);
  patch_stage2<<<1, 256, 0, stream>>>(ws, out, B, scale);
}